// Round 13
// baseline (1060.182 us; speedup 1.0000x reference)
//
#include <hip/hip_runtime.h>

// Problem constants (N=1)
constexpr int W_ = 160;   // input W (x), output dim 1
constexpr int H_ = 192;   // input H (y), output dim 2
constexpr int D_ = 64;    // input D (z), output dim 4 (innermost)
constexpr int C_ = 32;
constexpr int HW_  = H_ * W_;          // 30720
constexpr int DHWi = D_ * HW_;         // 1966080
constexpr int CD   = C_ * D_;          // 2048

// R12 verdict: instruction/address-rate model CONFIRMED (848K cy = 160 waves x
// 96 scattered loads x ~55 cy = ~1 lane-address/cycle TA throughput; L1-hit
// locality null, TLP null x3, ILP null). Only lever: remove scattered VMEM.
// R13: dense-stage + LDS-gather.
//  - tile (w:32,h:8,d:4), one c; 256 threads = one (w,h) + 4 d's each.
//  - runtime bounding box (R3's rigorous corner method) staged into a
//    COMPILE-TIME [BZ=9][BY=24][BX=44] LDS buffer (38 KB -> 4 blocks/CU);
//    stage rows are wave-uniform (gz,gy) + lane-contiguous x -> ~4 line
//    transactions per wave-load (vs ~64 scattered), batched 12-deep + pinned.
//  - ONE barrier per block lifetime; gather = 32 LDS reads (pinned) + blend
//    + one f4 NT store. TA demand ~848K -> ~200K cy/CU; LDS pipe ~240K.
//  - box too big (rare, theta-dependent) -> whole block falls back to the
//    proven R7 global-gather (correct, ~R7 speed).
// Keep frozen: L2 phase schedule (c,dt slowest per XCD), x-pair trick,
// value-pin anti-serialization, NT f4 stores, launch_bounds(256,4).
constexpr int TW = 32, THh = 8, TDt = 4;
constexpr int NWT = W_ / TW;             // 5
constexpr int NHT = H_ / THh;            // 24
constexpr int NDT = D_ / TDt;            // 16
constexpr int QPP = NWT * NHT;           // 120 spatial blocks per (c,dt) phase
constexpr int CPX = C_ / 8;              // 4 channels per XCD
constexpr int BX = 44, BY = 24, BZ = 9;  // staged box (compile-time strides)
constexpr int TOT = BX * BY * BZ;        // 9504 floats = 38016 B -> 4 blocks/CU

typedef float f4_t __attribute__((ext_vector_type(4)));
typedef float f2_t __attribute__((ext_vector_type(2)));

__global__ void __launch_bounds__(256, 4)
affine_grid_sample_kernel(const float* __restrict__ inp,
                          const float* __restrict__ th,
                          float* __restrict__ out)
{
    __shared__ float Lb[TOT];

    const int t   = threadIdx.x;
    const int bid = blockIdx.x;
    const int xcd = bid & 7;             // XCD id (dispatch round-robin)
    const int r   = bid >> 3;            // 0..7679 within XCD, dispatch order
    const int q   = r % QPP;             // spatial within phase
    const int rem = r / QPP;             // 0..63: (c_local, dt), dt fastest
    const int c   = xcd * CPX + (rem >> 4);
    const int dt  = rem & 15;            // consecutive phases share z-halo (L2)
    const int hs  = q / NWT;
    const int wt  = q - hs * NWT;
    const int w0 = wt * TW, h0 = hs * THh, d0 = dt * TDt;

    const float th0=th[0], th1=th[1], th2 =th[2],  th3 =th[3];
    const float th4=th[4], th5=th[5], th6 =th[6],  th7 =th[7];
    const float th8=th[8], th9=th[9], th10=th[10], th11=th[11];

    const float* __restrict__ pc = inp + (size_t)c * DHWi;

    // thread -> one (w,h), all 4 d's
    const int wl = t & 31;
    const int hl = t >> 5;               // 0..7
    const int w  = w0 + wl;
    const int h  = h0 + hl;
    const float xx = fmaf((float)w, 2.0f / (W_ - 1), -1.0f);
    const float yy = fmaf((float)h, 2.0f / (H_ - 1), -1.0f);

    // ---- rigorous bounding box from 8 tile corners (exact same expression
    // trees as the per-point eval; fma weakly monotone per argument) ----
    float pxmn= 1e30f, pxmx=-1e30f, pymn= 1e30f, pymx=-1e30f,
          pzmn= 1e30f, pzmx=-1e30f;
    #pragma unroll
    for (int ci = 0; ci < 8; ++ci) {
        const int cw = (ci & 1) ? w0 + TW  - 1 : w0;
        const int chh= (ci & 2) ? h0 + THh - 1 : h0;
        const int cd = (ci & 4) ? d0 + TDt - 1 : d0;
        const float zzc = fmaf((float)cd, 2.0f / (D_ - 1), -1.0f);
        const float kxc = fmaf(th2,  zzc, th3);
        const float kyc = fmaf(th6,  zzc, th7);
        const float kzc = fmaf(th10, zzc, th11);
        const float xxc = fmaf((float)cw,  2.0f / (W_ - 1), -1.0f);
        const float yyc = fmaf((float)chh, 2.0f / (H_ - 1), -1.0f);
        const float px = (fmaf(th0, xxc, fmaf(th1, yyc, kxc)) + 1.0f) * (0.5f * (W_ - 1));
        const float py = (fmaf(th4, xxc, fmaf(th5, yyc, kyc)) + 1.0f) * (0.5f * (H_ - 1));
        const float pz = (fmaf(th8, xxc, fmaf(th9, yyc, kzc)) + 1.0f) * (0.5f * (D_ - 1));
        pxmn = fminf(pxmn, px); pxmx = fmaxf(pxmx, px);
        pymn = fminf(pymn, py); pymx = fmaxf(pymx, py);
        pzmn = fminf(pzmn, pz); pzmx = fmaxf(pzmx, pz);
    }
    const int xlo = max((int)floorf(pxmn), 0);
    const int xhi = min((int)floorf(pxmx) + 1, W_ - 1);
    const int ylo = max((int)floorf(pymn), 0);
    const int yhi = min((int)floorf(pymx) + 1, H_ - 1);
    const int zlo = max((int)floorf(pzmn), 0);
    const int zhi = min((int)floorf(pzmx) + 1, D_ - 1);
    const bool fits = (xhi - xlo + 1 <= BX) && (yhi - ylo + 1 <= BY) &&
                      (zhi - zlo + 1 <= BZ);   // block-uniform

    // ---- per-d weights + clamped coords (shared by both paths) ----
    float wA[4], wB[4], v0a[4], v1a[4], s0a[4], s1a[4];
    int   E[4], CY0[4], CY1[4], CZ0[4], CZ1[4];
    #pragma unroll
    for (int k = 0; k < 4; ++k) {
        const int d = d0 + k;
        const float zz  = fmaf((float)d, 2.0f / (D_ - 1), -1.0f);
        const float kzx = fmaf(th2,  zz, th3);
        const float kzy = fmaf(th6,  zz, th7);
        const float kzz = fmaf(th10, zz, th11);
        const float px = (fmaf(th0, xx, fmaf(th1, yy, kzx)) + 1.0f) * (0.5f * (W_ - 1));
        const float py = (fmaf(th4, xx, fmaf(th5, yy, kzy)) + 1.0f) * (0.5f * (H_ - 1));
        const float pz = (fmaf(th8, xx, fmaf(th9, yy, kzz)) + 1.0f) * (0.5f * (D_ - 1));
        const float fx = floorf(px), fy = floorf(py), fz = floorf(pz);
        const int ix0 = (int)fx, iy0 = (int)fy, iz0 = (int)fz;
        const float wx = px - fx, wy = py - fy, wz = pz - fz;
        // zeros-padding: per-axis weight of any OOB corner is zeroed
        const float u0r = ((unsigned)ix0       < (unsigned)W_) ? (1.0f - wx) : 0.0f;
        const float u1r = ((unsigned)(ix0 + 1) < (unsigned)W_) ? wx          : 0.0f;
        v0a[k] = ((unsigned)iy0       < (unsigned)H_) ? (1.0f - wy) : 0.0f;
        v1a[k] = ((unsigned)(iy0 + 1) < (unsigned)H_) ? wy          : 0.0f;
        s0a[k] = ((unsigned)iz0       < (unsigned)D_) ? (1.0f - wz) : 0.0f;
        s1a[k] = ((unsigned)(iz0 + 1) < (unsigned)D_) ? wz          : 0.0f;
        // x-pair on base e=clamp(ix0,0,W-2): in-range (u0r,u1r);
        // ix0==-1 -> (u1r,0); ix0==W-1 -> (0,u0r); both-OOB already zero
        float a = u0r, b = u1r;
        if (ix0 == -1)     { a = u1r; b = 0.0f; }
        if (ix0 == W_ - 1) { a = 0.0f; b = u0r; }
        wA[k] = a; wB[k] = b;
        E[k]   = min(max(ix0,     0), W_ - 2);
        CY0[k] = min(max(iy0,     0), H_ - 1);
        CY1[k] = min(max(iy0 + 1, 0), H_ - 1);
        CZ0[k] = min(max(iz0,     0), D_ - 1);
        CZ1[k] = min(max(iz0 + 1, 0), D_ - 1);
    }

    float* const ob = out + ((size_t)w * H_ + h) * CD + (size_t)c * D_ + d0;
    f4_t val;

    if (fits) {
        // ---- stage: wave-structured full rows, coalesced, batched+pinned ----
        // wave wv stages rows by = wv, wv+4, ... of each bz plane; lane = x.
        const int wv = t >> 6, lane = t & 63;
        const bool lx = (lane < BX);
        const int gxl = min(xlo + lane, W_ - 1);
        #pragma unroll
        for (int rr = 0; rr < 4; ++rr) {      // bz pairs {0,1},{2,3},{4,5},{6,7}
            float v[12];
            #pragma unroll
            for (int bb = 0; bb < 2; ++bb) {
                const int bz = 2 * rr + bb;
                const int gz = min(zlo + bz, D_ - 1);
                const float* __restrict__ rowz = pc + gz * HW_;
                #pragma unroll
                for (int i = 0; i < 6; ++i) {
                    const int gy = min(ylo + wv + i * 4, H_ - 1);
                    v[bb * 6 + i] = lx ? rowz[gy * W_ + gxl] : 0.0f;
                }
            }
            asm volatile("" :: "v"(v[0]), "v"(v[1]), "v"(v[2]),  "v"(v[3]),
                               "v"(v[4]), "v"(v[5]), "v"(v[6]),  "v"(v[7]),
                               "v"(v[8]), "v"(v[9]), "v"(v[10]), "v"(v[11]));
            #pragma unroll
            for (int bb = 0; bb < 2; ++bb) {
                const int bz = 2 * rr + bb;
                #pragma unroll
                for (int i = 0; i < 6; ++i) {
                    const int by = wv + i * 4;
                    if (lx) Lb[(bz * BY + by) * BX + lane] = v[bb * 6 + i];
                }
            }
        }
        {   // bz = 8
            const int gz = min(zlo + 8, D_ - 1);
            const float* __restrict__ rowz = pc + gz * HW_;
            float v[6];
            #pragma unroll
            for (int i = 0; i < 6; ++i) {
                const int gy = min(ylo + wv + i * 4, H_ - 1);
                v[i] = lx ? rowz[gy * W_ + gxl] : 0.0f;
            }
            asm volatile("" :: "v"(v[0]), "v"(v[1]), "v"(v[2]),
                               "v"(v[3]), "v"(v[4]), "v"(v[5]));
            #pragma unroll
            for (int i = 0; i < 6; ++i) {
                const int by = wv + i * 4;
                if (lx) Lb[(8 * BY + by) * BX + lane] = v[i];
            }
        }
        __syncthreads();                     // the only barrier in the block

        // ---- gather: 32 LDS reads (batched + pinned), blend ----
        float p0[4][4], p1[4][4];
        #pragma unroll
        for (int k = 0; k < 4; ++k) {
            const int rx  = E[k] - xlo;
            const int r00 = ((CZ0[k] - zlo) * BY + (CY0[k] - ylo)) * BX + rx;
            const int r01 = ((CZ0[k] - zlo) * BY + (CY1[k] - ylo)) * BX + rx;
            const int r10 = ((CZ1[k] - zlo) * BY + (CY0[k] - ylo)) * BX + rx;
            const int r11 = ((CZ1[k] - zlo) * BY + (CY1[k] - ylo)) * BX + rx;
            p0[k][0] = Lb[r00]; p1[k][0] = Lb[r00 + 1];
            p0[k][1] = Lb[r01]; p1[k][1] = Lb[r01 + 1];
            p0[k][2] = Lb[r10]; p1[k][2] = Lb[r10 + 1];
            p0[k][3] = Lb[r11]; p1[k][3] = Lb[r11 + 1];
        }
        asm volatile("" ::
            "v"(p0[0][0]), "v"(p0[0][1]), "v"(p0[0][2]), "v"(p0[0][3]),
            "v"(p0[1][0]), "v"(p0[1][1]), "v"(p0[1][2]), "v"(p0[1][3]),
            "v"(p0[2][0]), "v"(p0[2][1]), "v"(p0[2][2]), "v"(p0[2][3]),
            "v"(p0[3][0]), "v"(p0[3][1]), "v"(p0[3][2]), "v"(p0[3][3]),
            "v"(p1[0][0]), "v"(p1[0][1]), "v"(p1[0][2]), "v"(p1[0][3]),
            "v"(p1[1][0]), "v"(p1[1][1]), "v"(p1[1][2]), "v"(p1[1][3]),
            "v"(p1[2][0]), "v"(p1[2][1]), "v"(p1[2][2]), "v"(p1[2][3]),
            "v"(p1[3][0]), "v"(p1[3][1]), "v"(p1[3][2]), "v"(p1[3][3]));
        __builtin_amdgcn_sched_barrier(0);
        #pragma unroll
        for (int k = 0; k < 4; ++k) {
            const float x00 = wA[k] * p0[k][0] + wB[k] * p1[k][0];
            const float x01 = wA[k] * p0[k][1] + wB[k] * p1[k][1];
            const float x10 = wA[k] * p0[k][2] + wB[k] * p1[k][2];
            const float x11 = wA[k] * p0[k][3] + wB[k] * p1[k][3];
            const float e0 = v0a[k] * x00 + v1a[k] * x01;
            const float e1 = v0a[k] * x10 + v1a[k] * x11;
            val[k] = s0a[k] * e0 + s1a[k] * e1;
        }
    } else {
        // ---- fallback: proven R7 global x-pair gather (rare) ----
        f2_t P[4][4];
        #pragma unroll
        for (int k = 0; k < 4; ++k) {
            const unsigned o0 = (unsigned)(CZ0[k] * HW_ + CY0[k] * W_ + E[k]);
            const unsigned o1 = (unsigned)(CZ0[k] * HW_ + CY1[k] * W_ + E[k]);
            const unsigned o2 = (unsigned)(CZ1[k] * HW_ + CY0[k] * W_ + E[k]);
            const unsigned o3 = (unsigned)(CZ1[k] * HW_ + CY1[k] * W_ + E[k]);
            __builtin_memcpy(&P[k][0], pc + o0, 8);
            __builtin_memcpy(&P[k][1], pc + o1, 8);
            __builtin_memcpy(&P[k][2], pc + o2, 8);
            __builtin_memcpy(&P[k][3], pc + o3, 8);
        }
        asm volatile("" ::
            "v"(P[0][0]), "v"(P[0][1]), "v"(P[0][2]), "v"(P[0][3]),
            "v"(P[1][0]), "v"(P[1][1]), "v"(P[1][2]), "v"(P[1][3]),
            "v"(P[2][0]), "v"(P[2][1]), "v"(P[2][2]), "v"(P[2][3]),
            "v"(P[3][0]), "v"(P[3][1]), "v"(P[3][2]), "v"(P[3][3]));
        __builtin_amdgcn_sched_barrier(0);
        #pragma unroll
        for (int k = 0; k < 4; ++k) {
            const float x00 = wA[k] * P[k][0][0] + wB[k] * P[k][0][1];
            const float x01 = wA[k] * P[k][1][0] + wB[k] * P[k][1][1];
            const float x10 = wA[k] * P[k][2][0] + wB[k] * P[k][2][1];
            const float x11 = wA[k] * P[k][3][0] + wB[k] * P[k][3][1];
            const float e0 = v0a[k] * x00 + v1a[k] * x01;
            const float e1 = v0a[k] * x10 + v1a[k] * x11;
            val[k] = s0a[k] * e0 + s1a[k] * e1;
        }
    }

    // output is write-once streaming: non-temporal 16B store
    __builtin_nontemporal_store(val, (f4_t*)ob);
}

extern "C" void kernel_launch(void* const* d_in, const int* in_sizes, int n_in,
                              void* d_out, int out_size, void* d_ws, size_t ws_size,
                              hipStream_t stream)
{
    const float* inp = (const float*)d_in[0];   // [1,32,64,192,160] fp32
    const float* th  = (const float*)d_in[1];   // 12 fp32
    float* out = (float*)d_out;                 // [1,160,192,32,64] fp32

    // 8 XCD x (4 c x 16 dt phases) x 120 spatial = 61440 blocks
    hipLaunchKernelGGL(affine_grid_sample_kernel, dim3(8 * CPX * NDT * QPP),
                       dim3(256), 0, stream, inp, th, out);
}

// Round 14
// 640.077 us; speedup vs baseline: 1.6563x; 1.6563x over previous
//
#include <hip/hip_runtime.h>

// Problem constants (N=1)
constexpr int W_ = 160;   // input W (x)
constexpr int H_ = 192;   // input H (y)
constexpr int D_ = 64;    // input D (z)
constexpr int C_ = 32;
constexpr int HW_  = H_ * W_;          // 30720
constexpr int DHWi = D_ * HW_;         // 1966080
constexpr int CD   = C_ * D_;          // 2048

// R13 post-mortem: LDS-gather theory untested -- impl died of (1) spill
// (WRITE 246->494MB: pins + per-d arrays live across staging), (2) 19M bank
// conflicts, (3) tiny tile (9.3x staging redundancy). R14 re-engineering:
//  - staging via __builtin_amdgcn_global_load_lds: NO dest VGPRs -> spill and
//    allocator-serialization structurally impossible; LDS dest = uniform base
//    + lane*4 -> with fixed BX=32 rows, ONE instr stages TWO rows (lanes 0-31
//    row r, 32-63 row r+1; per-lane global addr, clamped). One vmcnt(0) +
//    ONE barrier per block.
//  - compile-time LDS row stride (32 floats -> shifts); only BY runtime
//    (one mad per tap; 18-bit magic for staging row->(bz,by)).
//  - weights/indices computed AFTER the barrier (tiny live state across it).
//  - tile (w:16,h:8,d:16), one c, 2048 outputs; est. box 21x17x19 -> R~323
//    <= 420 cap (30% margin); LDS 54KB -> 3 blocks/CU. Block-uniform fallback
//    = proven R7 global x-pair gather.
// Keep frozen: XCD phase schedule, exact fp expression trees, x-pair weight
// shuffle, NT stores.
constexpr int TW = 16, TH = 8, TD = 16;
constexpr int NWT = W_ / TW;             // 10
constexpr int NHT = H_ / TH;             // 24
constexpr int NDT = D_ / TD;             // 4
constexpr int QPP = NWT * NHT;           // 240 spatial blocks per (c,dt) phase
constexpr int CPX = C_ / 8;              // 4 channels per XCD
constexpr int BXF   = 32;                // fixed LDS row width (floats)
constexpr int RMAX  = 420;               // max staged rows (BZr*BYr)
constexpr int LROWS = RMAX + 2;          // +2: pair staging may touch row R(+1)
// LDS = 32*422*4 = 54016 B -> 3 blocks/CU (<= 54613)

typedef float f4_t __attribute__((ext_vector_type(4)));
typedef float f2_t __attribute__((ext_vector_type(2)));

__global__ void __launch_bounds__(256, 4)
affine_grid_sample_kernel(const float* __restrict__ inp,
                          const float* __restrict__ th,
                          float* __restrict__ out)
{
    __shared__ float Lb[BXF * LROWS];

    const int t   = threadIdx.x;
    const int bid = blockIdx.x;
    const int xcd = bid & 7;             // XCD id (dispatch round-robin)
    const int r_  = bid >> 3;            // 0..3839 within XCD, dispatch order
    const int q   = r_ % QPP;
    const int rem = r_ / QPP;            // 0..15: (c_local, dt), dt fastest
    const int c   = xcd * CPX + (rem >> 2);
    const int dt  = rem & 3;
    const int hs  = q / NWT;
    const int wt  = q - hs * NWT;
    const int w0 = wt * TW, h0 = hs * TH, d0 = dt * TD;

    const float th0=th[0], th1=th[1], th2 =th[2],  th3 =th[3];
    const float th4=th[4], th5=th[5], th6 =th[6],  th7 =th[7];
    const float th8=th[8], th9=th[9], th10=th[10], th11=th[11];

    const float* __restrict__ pc = inp + (size_t)c * DHWi;

    // ---- rigorous bounding box from 8 tile corners (same fp trees as the
    // per-point eval; fma weakly monotone per argument) -- block-uniform ----
    float pxmn= 1e30f, pxmx=-1e30f, pymn= 1e30f, pymx=-1e30f,
          pzmn= 1e30f, pzmx=-1e30f;
    #pragma unroll
    for (int ci = 0; ci < 8; ++ci) {
        const int cw = (ci & 1) ? w0 + TW - 1 : w0;
        const int chh= (ci & 2) ? h0 + TH - 1 : h0;
        const int cd = (ci & 4) ? d0 + TD - 1 : d0;
        const float zzc = fmaf((float)cd, 2.0f / (D_ - 1), -1.0f);
        const float kxc = fmaf(th2,  zzc, th3);
        const float kyc = fmaf(th6,  zzc, th7);
        const float kzc = fmaf(th10, zzc, th11);
        const float xxc = fmaf((float)cw,  2.0f / (W_ - 1), -1.0f);
        const float yyc = fmaf((float)chh, 2.0f / (H_ - 1), -1.0f);
        const float px = (fmaf(th0, xxc, fmaf(th1, yyc, kxc)) + 1.0f) * (0.5f * (W_ - 1));
        const float py = (fmaf(th4, xxc, fmaf(th5, yyc, kyc)) + 1.0f) * (0.5f * (H_ - 1));
        const float pz = (fmaf(th8, xxc, fmaf(th9, yyc, kzc)) + 1.0f) * (0.5f * (D_ - 1));
        pxmn = fminf(pxmn, px); pxmx = fmaxf(pxmx, px);
        pymn = fminf(pymn, py); pymx = fmaxf(pymx, py);
        pzmn = fminf(pzmn, pz); pzmx = fmaxf(pzmx, pz);
    }
    const int xlo = max((int)floorf(pxmn), 0);
    const int xhi = min((int)floorf(pxmx) + 1, W_ - 1);
    const int ylo = max((int)floorf(pymn), 0);
    const int yhi = min((int)floorf(pymx) + 1, H_ - 1);
    const int zlo = max((int)floorf(pzmn), 0);
    const int zhi = min((int)floorf(pzmx) + 1, D_ - 1);
    const int BXr = xhi - xlo + 1;
    const int BYr = yhi - ylo + 1;
    const int BZr = zhi - zlo + 1;
    const int R   = BZr * BYr;
    const bool fits = (BXr <= BXF) && (BYr <= 128) && (R <= RMAX);

    if (fits) {
        // ---- stage: global_load_lds, 2 rows per instruction, no VGPR dest --
        const int lane = t & 63, wv = t >> 6;
        const int half = lane >> 5;          // which row of the pair
        const int lx   = lane & 31;          // x within row
        const unsigned m18 = (262144u + (unsigned)BYr - 1) / (unsigned)BYr;
        const int npair = (R + 1) >> 1;
        for (int p = wv; p < npair; p += 4) {
            const int rr = 2 * p + half;     // per-lane logical row
            const int bz = (int)(((unsigned)rr * m18) >> 18);  // exact: rr<2^18/BYr
            const int by = rr - bz * BYr;
            const int gz = min(zlo + bz, D_ - 1);              // pad row: clamp
            const int gy = min(ylo + by, H_ - 1);
            const int gx = min(xlo + lx, W_ - 1);              // clamp: no OOB read
            const float* gsrc = pc + ((unsigned)(gz * HW_ + gy * W_ + gx));
            // LDS dest = wave-uniform base + lane*4 (HW adds the lane term)
            __builtin_amdgcn_global_load_lds(
                (const __attribute__((address_space(1))) unsigned*)gsrc,
                (__attribute__((address_space(3))) unsigned*)&Lb[(2 * p) * BXF],
                4, 0, 0);
        }
        asm volatile("s_waitcnt vmcnt(0)" ::: "memory");
    }
    __syncthreads();                         // the only barrier in the block

    // ---- per-thread output map: (dq, wl, hl); lane pairs cover contiguous
    // 32B output segments along d ----
    const int dq = t & 1;                    // which half of the d-16 run
    const int wl = (t >> 1) & 15;
    const int hl = t >> 5;                   // 0..7
    const int w  = w0 + wl;
    const int h  = h0 + hl;
    const float xx = fmaf((float)w, 2.0f / (W_ - 1), -1.0f);
    const float yy = fmaf((float)h, 2.0f / (H_ - 1), -1.0f);

    f4_t val0, val1;
    #pragma unroll
    for (int k = 0; k < 8; ++k) {
        // d-split: k 0..3 -> d0+dq*4+k; k 4..7 -> d0+8+dq*4+(k-4)
        const int d = d0 + (k & 3) + dq * 4 + (k >> 2) * 8;
        const float zz  = fmaf((float)d, 2.0f / (D_ - 1), -1.0f);
        const float kzx = fmaf(th2,  zz, th3);
        const float kzy = fmaf(th6,  zz, th7);
        const float kzz = fmaf(th10, zz, th11);
        const float px = (fmaf(th0, xx, fmaf(th1, yy, kzx)) + 1.0f) * (0.5f * (W_ - 1));
        const float py = (fmaf(th4, xx, fmaf(th5, yy, kzy)) + 1.0f) * (0.5f * (H_ - 1));
        const float pz = (fmaf(th8, xx, fmaf(th9, yy, kzz)) + 1.0f) * (0.5f * (D_ - 1));
        const float fx = floorf(px), fy = floorf(py), fz = floorf(pz);
        const int ix0 = (int)fx, iy0 = (int)fy, iz0 = (int)fz;
        const float wx = px - fx, wy = py - fy, wz = pz - fz;
        // zeros-padding: per-axis weight of any OOB corner is zeroed
        const float u0r = ((unsigned)ix0       < (unsigned)W_) ? (1.0f - wx) : 0.0f;
        const float u1r = ((unsigned)(ix0 + 1) < (unsigned)W_) ? wx          : 0.0f;
        const float v0  = ((unsigned)iy0       < (unsigned)H_) ? (1.0f - wy) : 0.0f;
        const float v1  = ((unsigned)(iy0 + 1) < (unsigned)H_) ? wy          : 0.0f;
        const float s0  = ((unsigned)iz0       < (unsigned)D_) ? (1.0f - wz) : 0.0f;
        const float s1  = ((unsigned)(iz0 + 1) < (unsigned)D_) ? wz          : 0.0f;
        // x-pair weights on base e=clamp(ix0,0,W-2): in-range (u0r,u1r);
        // ix0==-1 -> (u1r,0); ix0==W-1 -> (0,u0r); both-OOB already zero
        float wA = u0r, wB = u1r;
        if (ix0 == -1)     { wA = u1r; wB = 0.0f; }
        if (ix0 == W_ - 1) { wA = 0.0f; wB = u0r; }
        const int e   = min(max(ix0,     0), W_ - 2);
        const int cy0 = min(max(iy0,     0), H_ - 1);
        const int cy1 = min(max(iy0 + 1, 0), H_ - 1);
        const int cz0 = min(max(iz0,     0), D_ - 1);
        const int cz1 = min(max(iz0 + 1, 0), D_ - 1);

        float a00, b00, a01, b01, a10, b10, a11, b11;
        if (__builtin_expect(fits, 1)) {
            // taps guaranteed inside the box (monotone corner bounds + clamps)
            const int bx  = e - xlo;
            const int r00 = (cz0 - zlo) * BYr + (cy0 - ylo);
            const int r01 = (cz0 - zlo) * BYr + (cy1 - ylo);
            const int r10 = (cz1 - zlo) * BYr + (cy0 - ylo);
            const int r11 = (cz1 - zlo) * BYr + (cy1 - ylo);
            const float* L00 = &Lb[(r00 << 5) + bx];   // compile-time stride 32
            const float* L01 = &Lb[(r01 << 5) + bx];
            const float* L10 = &Lb[(r10 << 5) + bx];
            const float* L11 = &Lb[(r11 << 5) + bx];
            a00 = L00[0]; b00 = L00[1];                // ds_read2_b32 pairs
            a01 = L01[0]; b01 = L01[1];
            a10 = L10[0]; b10 = L10[1];
            a11 = L11[0]; b11 = L11[1];
        } else {
            // fallback: proven R7 global x-pair gather (rare)
            f2_t P0, P1, P2, P3;
            const unsigned o0 = (unsigned)(cz0 * HW_ + cy0 * W_ + e);
            const unsigned o1 = (unsigned)(cz0 * HW_ + cy1 * W_ + e);
            const unsigned o2 = (unsigned)(cz1 * HW_ + cy0 * W_ + e);
            const unsigned o3 = (unsigned)(cz1 * HW_ + cy1 * W_ + e);
            __builtin_memcpy(&P0, pc + o0, 8);
            __builtin_memcpy(&P1, pc + o1, 8);
            __builtin_memcpy(&P2, pc + o2, 8);
            __builtin_memcpy(&P3, pc + o3, 8);
            asm volatile("" :: "v"(P0), "v"(P1), "v"(P2), "v"(P3));
            a00 = P0[0]; b00 = P0[1]; a01 = P1[0]; b01 = P1[1];
            a10 = P2[0]; b10 = P2[1]; a11 = P3[0]; b11 = P3[1];
        }

        const float x00 = wA * a00 + wB * b00;
        const float x01 = wA * a01 + wB * b01;
        const float x10 = wA * a10 + wB * b10;
        const float x11 = wA * a11 + wB * b11;
        const float e0 = v0 * x00 + v1 * x01;
        const float e1 = v0 * x10 + v1 * x11;
        const float v  = s0 * e0 + s1 * e1;
        if (k < 4) val0[k] = v; else val1[k - 4] = v;
    }

    // ---- stores: 2 NT f4 per thread; lane pairs form contiguous 32B runs ----
    float* const ob = out + ((size_t)w * H_ + h) * CD + (size_t)c * D_ + d0 + dq * 4;
    __builtin_nontemporal_store(val0, (f4_t*)ob);
    __builtin_nontemporal_store(val1, (f4_t*)(ob + 8));
}

extern "C" void kernel_launch(void* const* d_in, const int* in_sizes, int n_in,
                              void* d_out, int out_size, void* d_ws, size_t ws_size,
                              hipStream_t stream)
{
    const float* inp = (const float*)d_in[0];   // [1,32,64,192,160] fp32
    const float* th  = (const float*)d_in[1];   // 12 fp32
    float* out = (float*)d_out;                 // [1,160,192,32,64] fp32

    // 8 XCD x (4 c x 4 dt phases) x 240 spatial = 30720 blocks
    hipLaunchKernelGGL(affine_grid_sample_kernel, dim3(8 * CPX * NDT * QPP),
                       dim3(256), 0, stream, inp, th, out);
}